// Round 5
// baseline (444.762 us; speedup 1.0000x reference)
//
#include <hip/hip_runtime.h>

// ---------- common ----------
typedef __bf16 bfv8 __attribute__((ext_vector_type(8)));
typedef float f32x4 __attribute__((ext_vector_type(4)));

#define DMODEL 2048
#define NHEADS 16
#define HEADD 128
#define SEQ 2048
#define BATCH 2
#define MROWS (BATCH * SEQ)   // 4096

__device__ __forceinline__ unsigned short f2bf(float f) {
    unsigned int x = __float_as_uint(f);
    x += 0x7fffu + ((x >> 16) & 1u);   // round-to-nearest-even
    return (unsigned short)(x >> 16);
}
__device__ __forceinline__ unsigned int pk2(float a, float b) {
    return (unsigned int)f2bf(a) | ((unsigned int)f2bf(b) << 16);
}

// ---------- fused fp32 -> bf16 convert for x + 4 weights (dst contiguous in ws) ----------
__global__ __launch_bounds__(256) void cvt_all(const float* __restrict__ x,
                                               const float* __restrict__ wq,
                                               const float* __restrict__ wk,
                                               const float* __restrict__ wv,
                                               const float* __restrict__ wo,
                                               unsigned short* __restrict__ dst) {
    int bid = blockIdx.x;
    const float* s;
    int off;
    if (bid < 8192)       { s = x;  off = bid; }
    else if (bid < 12288) { s = wq; off = bid - 8192; }
    else if (bid < 16384) { s = wk; off = bid - 12288; }
    else if (bid < 20480) { s = wv; off = bid - 16384; }
    else                  { s = wo; off = bid - 20480; }
    int i = off * 1024 + threadIdx.x * 4;
    float4 v = *(const float4*)(s + i);
    ushort4 o;
    o.x = f2bf(v.x); o.y = f2bf(v.y); o.z = f2bf(v.z); o.w = f2bf(v.w);
    *(ushort4*)(dst + (size_t)bid * 1024 + threadIdx.x * 4) = o;
}

// ============================================================
// global_load_lds staging into XOR-swizzled unpadded LDS.
// CPRL = log2(16B-chunks per row). Stored chunk c holds global
// chunk g = c ^ (row & 7).
// ============================================================
template <int CPRL, int ITERS>
__device__ __forceinline__ void stage_n(const unsigned short* __restrict__ gbase,
                                        unsigned short* lds, size_t strideShorts,
                                        int wave, int lane) {
#pragma unroll
    for (int i = 0; i < ITERS; ++i) {
        int L = wave * (64 * ITERS) + i * 64 + lane;
        int m = L >> CPRL, c = L & ((1 << CPRL) - 1);
        int g = c ^ (m & 7);
        const unsigned short* gp = gbase + (size_t)m * strideShorts + g * 8;
        __builtin_amdgcn_global_load_lds(
            (const __attribute__((address_space(1))) unsigned int*)gp,
            (__attribute__((address_space(3))) unsigned int*)(lds + (size_t)(wave * (64 * ITERS) + i * 64) * 8),
            16, 0, 0);
    }
}

#define GBK 64

// ---------- fused QKV GEMM + RoPE + per-head LN epilogue ----------
// A[4096][2048] x Wcat[6144][2048]^T; region 0 -> Q bf16 (rope+LN+scale),
// 1 -> K bf16 (rope+LN), 2 -> V bf16 transposed per head
__global__ __launch_bounds__(256, 4) void gemm_qkv(const unsigned short* __restrict__ A,
                                                   const unsigned short* __restrict__ Bw,
                                                   unsigned short* __restrict__ Qb,
                                                   unsigned short* __restrict__ Kb,
                                                   unsigned short* __restrict__ VT,
                                                   const float* __restrict__ qnw,
                                                   const float* __restrict__ knw) {
    __shared__ __align__(16) unsigned short As[128 * 64];
    __shared__ __align__(16) unsigned short Bs[128 * 64];
    const int K = DMODEL;
    int tid  = threadIdx.x;
    int bm   = blockIdx.y * 128, bn = blockIdx.x * 128;
    int wave = tid >> 6, lane = tid & 63;
    int wm   = (wave >> 1) * 64, wn = (wave & 1) * 64;
    int lr   = lane & 15, lg = lane >> 4;

    f32x4 acc[4][4];
    f32x4 z = {0.f, 0.f, 0.f, 0.f};
#pragma unroll
    for (int i = 0; i < 4; ++i)
#pragma unroll
        for (int j = 0; j < 4; ++j) acc[i][j] = z;

    const unsigned short* Ab = A  + (size_t)bm * K;
    const unsigned short* Bb = Bw + (size_t)bn * K;

    for (int k0 = 0; k0 < K; k0 += GBK) {
        __syncthreads();
        stage_n<3, 4>(Ab + k0, As, K, wave, lane);
        stage_n<3, 4>(Bb + k0, Bs, K, wave, lane);
        __syncthreads();
#pragma unroll
        for (int kk = 0; kk < GBK; kk += 32) {
            int ck = (kk >> 3) + lg;
            bfv8 af[4], bf[4];
#pragma unroll
            for (int i = 0; i < 4; ++i)
                af[i] = *(const bfv8*)&As[(wm + i * 16 + lr) * 64 + (ck ^ (lr & 7)) * 8];
#pragma unroll
            for (int j = 0; j < 4; ++j)
                bf[j] = *(const bfv8*)&Bs[(wn + j * 16 + lr) * 64 + (ck ^ (lr & 7)) * 8];
#pragma unroll
            for (int i = 0; i < 4; ++i)
#pragma unroll
                for (int j = 0; j < 4; ++j)
                    acc[i][j] = __builtin_amdgcn_mfma_f32_16x16x32_bf16(af[i], bf[j], acc[i][j], 0, 0, 0);
        }
    }
    int lm = lr;
    int region = bn >> 11;          // block-uniform: 0=Q 1=K 2=V
    int nloc   = bn & 2047;
    if (region < 2) {
        unsigned short* C = region ? Kb : Qb;
        const float* nw = region ? knw : qnw;
        float scale = region ? 1.0f : 0.08838834764831845f;   // fold 1/sqrt(128) into Q
        float invf[4], wnw[4];
#pragma unroll
        for (int j = 0; j < 4; ++j) {
            int dd = wn + j * 16 + lm;                         // dim-in-head
            invf[j] = exp2f(-(float)(dd >> 1) * 0.20762050593046f);  // 10000^(-f/64)
            wnw[j] = nw[dd];
        }
        int sbase = (bm & (SEQ - 1)) + wm + lg * 4;            // block rows stay in one batch
        // RoPE in place (pair partner lives in lane lm^1, same j)
#pragma unroll
        for (int i = 0; i < 4; ++i)
#pragma unroll
            for (int r = 0; r < 4; ++r) {
                float sv = (float)(sbase + i * 16 + r);
#pragma unroll
                for (int j = 0; j < 4; ++j) {
                    float sn, cs;
                    __sincosf(sv * invf[j], &sn, &cs);
                    float x0 = acc[i][j][r];
                    float x1 = __shfl_xor(x0, 1);
                    acc[i][j][r] = (lm & 1) ? fmaf(x1, sn, x0 * cs)
                                            : fmaf(x0, cs, -(x1 * sn));
                }
            }
        // per-row LN over 128 dims: wave-half partials -> LDS -> combine
        float* red = (float*)As;    // 128 rows x 2 halves x 2 stats = 2 KB
        int half = wn >> 6;
        __syncthreads();            // everyone done reading As/Bs
#pragma unroll
        for (int i = 0; i < 4; ++i)
#pragma unroll
            for (int r = 0; r < 4; ++r) {
                float a0 = acc[i][0][r], a1 = acc[i][1][r], a2 = acc[i][2][r], a3 = acc[i][3][r];
                float s1 = (a0 + a1) + (a2 + a3);
                float s2 = fmaf(a0, a0, fmaf(a1, a1, fmaf(a2, a2, a3 * a3)));
#pragma unroll
                for (int msk = 1; msk <= 8; msk <<= 1) {
                    s1 += __shfl_xor(s1, msk);
                    s2 += __shfl_xor(s2, msk);
                }
                if (lm == 0) {
                    int rloc = wm + lg * 4 + i * 16 + r;
                    red[(rloc * 2 + half) * 2 + 0] = s1;
                    red[(rloc * 2 + half) * 2 + 1] = s2;
                }
            }
        __syncthreads();
#pragma unroll
        for (int i = 0; i < 4; ++i)
#pragma unroll
            for (int r = 0; r < 4; ++r) {
                int rloc = wm + lg * 4 + i * 16 + r;
                float t1 = red[(rloc * 2 + 0) * 2 + 0] + red[(rloc * 2 + 1) * 2 + 0];
                float t2 = red[(rloc * 2 + 0) * 2 + 1] + red[(rloc * 2 + 1) * 2 + 1];
                float mu  = t1 * (1.0f / 128.0f);
                float var = t2 * (1.0f / 128.0f) - mu * mu;
                float rs  = rsqrtf(var + 1e-5f) * scale;
                size_t rowoff = (size_t)(bm + rloc) * DMODEL + nloc;
#pragma unroll
                for (int j = 0; j < 4; ++j)
                    C[rowoff + wn + j * 16 + lm] = f2bf((acc[i][j][r] - mu) * rs * wnw[j]);
            }
    } else {
        int orow0 = bm + wm + lg * 4;
#pragma unroll
        for (int i = 0; i < 4; ++i) {
            int row = orow0 + i * 16;
            int bb = row >> 11, ss = row & (SEQ - 1);
#pragma unroll
            for (int j = 0; j < 4; ++j) {
                int col = nloc + wn + j * 16 + lm;
                int hh = col >> 7, dd = col & (HEADD - 1);
                ushort4 o4;
                o4.x = f2bf(acc[i][j][0]);
                o4.y = f2bf(acc[i][j][1]);
                o4.z = f2bf(acc[i][j][2]);
                o4.w = f2bf(acc[i][j][3]);
                *(ushort4*)(VT + ((size_t)((bb * NHEADS + hh) * HEADD + dd)) * SEQ + ss) = o4;
            }
        }
    }
}

// ---------- plain GEMM (fp32 out): C[M][N] = A[M][K] * Bw[N][K]^T ----------
__global__ __launch_bounds__(256) void gemm_bt(const unsigned short* __restrict__ A,
                                               const unsigned short* __restrict__ Bw,
                                               float* __restrict__ C,
                                               int M, int N, int K) {
    __shared__ __align__(16) unsigned short As[128 * 64];
    __shared__ __align__(16) unsigned short Bs[128 * 64];
    int tid  = threadIdx.x;
    int bm   = blockIdx.y * 128, bn = blockIdx.x * 128;
    int wave = tid >> 6, lane = tid & 63;
    int wm   = (wave >> 1) * 64, wn = (wave & 1) * 64;
    int lr   = lane & 15, lg = lane >> 4;

    f32x4 acc[4][4];
    f32x4 z = {0.f, 0.f, 0.f, 0.f};
#pragma unroll
    for (int i = 0; i < 4; ++i)
#pragma unroll
        for (int j = 0; j < 4; ++j) acc[i][j] = z;

    const unsigned short* Ab = A  + (size_t)bm * K;
    const unsigned short* Bb = Bw + (size_t)bn * K;

    for (int k0 = 0; k0 < K; k0 += GBK) {
        __syncthreads();
        stage_n<3, 4>(Ab + k0, As, K, wave, lane);
        stage_n<3, 4>(Bb + k0, Bs, K, wave, lane);
        __syncthreads();
#pragma unroll
        for (int kk = 0; kk < GBK; kk += 32) {
            int ck = (kk >> 3) + lg;
            bfv8 af[4], bf[4];
#pragma unroll
            for (int i = 0; i < 4; ++i)
                af[i] = *(const bfv8*)&As[(wm + i * 16 + lr) * 64 + (ck ^ (lr & 7)) * 8];
#pragma unroll
            for (int j = 0; j < 4; ++j)
                bf[j] = *(const bfv8*)&Bs[(wn + j * 16 + lr) * 64 + (ck ^ (lr & 7)) * 8];
#pragma unroll
            for (int i = 0; i < 4; ++i)
#pragma unroll
                for (int j = 0; j < 4; ++j)
                    acc[i][j] = __builtin_amdgcn_mfma_f32_16x16x32_bf16(af[i], bf[j], acc[i][j], 0, 0, 0);
        }
    }
    int orow0 = bm + wm + lg * 4;
    int ocol0 = bn + wn + lr;
#pragma unroll
    for (int i = 0; i < 4; ++i)
#pragma unroll
        for (int j = 0; j < 4; ++j)
#pragma unroll
            for (int r = 0; r < 4; ++r)
                C[(size_t)(orow0 + i * 16 + r) * N + ocol0 + j * 16] = acc[i][j][r];
}

// ---------- bf16 MFMA flash attention: 128q x 128k tiles, V from global/L2 ----------
#define AQT 128
#define AKT 128

__global__ __launch_bounds__(256, 2) void attn_mfma(const unsigned short* __restrict__ qb,
                                                    const unsigned short* __restrict__ kb,
                                                    const unsigned short* __restrict__ vt,
                                                    unsigned short* __restrict__ ob,
                                                    const int* __restrict__ wptr) {
    __shared__ __align__(16) unsigned short Ks[128 * 128];    // 32 KB swizzled
    __shared__ __align__(16) unsigned short Ps[4 * 32 * 128]; // 32 KB (per-wave P)
    int tid  = threadIdx.x;
    int wq   = tid >> 6, lane = tid & 63;
    int lm   = lane & 15, lg = lane >> 4;
    int lm7  = lm & 7;
    // XCD-grouped, heavy-first
    int gid  = blockIdx.x;
    int xcd  = gid & 7, slot = gid >> 3;   // 64 slots/xcd
    int bh   = xcd * 4 + (slot >> 4);
    int b    = bh >> 4, h = bh & 15;
    int q0   = (15 - (slot & 15)) * AQT;
    int W    = *wptr;
    unsigned short* PsW = &Ps[wq * 32 * 128];

    // Q B-fragments: 32 queries/wave (nq = 0,1), scale pre-folded
    bfv8 qa[2][4];
#pragma unroll
    for (int nq = 0; nq < 2; ++nq) {
        const unsigned short* qp = qb + (size_t)(b * SEQ + q0 + wq * 32 + nq * 16 + lm) * DMODEL + h * HEADD + lg * 8;
#pragma unroll
        for (int kk = 0; kk < 4; ++kk) qa[nq][kk] = *(const bfv8*)(qp + kk * 32);
    }

    f32x4 o[2][8];
    f32x4 z = {0.f, 0.f, 0.f, 0.f};
#pragma unroll
    for (int mq = 0; mq < 2; ++mq)
#pragma unroll
        for (int n = 0; n < 8; ++n) o[mq][n] = z;
    float mrow[2] = {-1e30f, -1e30f}, lrow[2] = {0.f, 0.f};

    const unsigned short* kbase = kb + (size_t)(b * SEQ) * DMODEL + h * HEADD;
    const unsigned short* vbase = vt + (size_t)((b * NHEADS + h) * HEADD) * SEQ;

    int kt_lo = max(0, q0 - W) & ~(AKT - 1);
    int qi0 = q0 + wq * 32 + lm;     // softmax-layout query for nq: qi0 + nq*16

    for (int kt = kt_lo; kt < q0 + AQT; kt += AKT) {
        __syncthreads();
        stage_n<4, 8>(kbase + (size_t)kt * DMODEL, Ks, DMODEL, wq, lane);  // 128 x 128
        __syncthreads();

        // S^T = K Q^T : [128 key][32 query] per wave
        f32x4 s[8][2];
#pragma unroll
        for (int j = 0; j < 8; ++j) { s[j][0] = z; s[j][1] = z; }
#pragma unroll
        for (int kk = 0; kk < 4; ++kk)
#pragma unroll
            for (int j = 0; j < 8; ++j) {
                bfv8 af = *(const bfv8*)&Ks[(j * 16 + lm) * 128 + (((kk * 4 + lg)) ^ lm7) * 8];
                s[j][0] = __builtin_amdgcn_mfma_f32_16x16x32_bf16(af, qa[0][kk], s[j][0], 0, 0, 0);
                s[j][1] = __builtin_amdgcn_mfma_f32_16x16x32_bf16(af, qa[1][kk], s[j][1], 0, 0, 0);
            }
        // mask only edge tiles (wave-uniform)
        if ((kt + AKT - 1 > q0) || (kt < q0 + AQT - 1 - W)) {
#pragma unroll
            for (int j = 0; j < 8; ++j) {
                int kj0 = kt + j * 16 + lg * 4;
#pragma unroll
                for (int nq = 0; nq < 2; ++nq) {
                    int qi = qi0 + nq * 16;
#pragma unroll
                    for (int r = 0; r < 4; ++r) {
                        bool ok = (kj0 + r <= qi) && (kj0 + r >= qi - W);
                        s[j][nq][r] = ok ? s[j][nq][r] : -1e30f;
                    }
                }
            }
        }
        // online softmax (2 queries per lane; reduce across lg: masks 16, 32)
        float alpha[2];
#pragma unroll
        for (int nq = 0; nq < 2; ++nq) {
            float mx = -1e30f;
#pragma unroll
            for (int j = 0; j < 8; ++j)
#pragma unroll
                for (int r = 0; r < 4; ++r) mx = fmaxf(mx, s[j][nq][r]);
            mx = fmaxf(mx, __shfl_xor(mx, 16));
            mx = fmaxf(mx, __shfl_xor(mx, 32));
            float mnew = fmaxf(mrow[nq], mx);
            alpha[nq] = __expf(mrow[nq] - mnew);
            mrow[nq] = mnew;
            float ls = 0.f;
#pragma unroll
            for (int j = 0; j < 8; ++j) {
                float p0 = __expf(s[j][nq][0] - mnew);
                float p1 = __expf(s[j][nq][1] - mnew);
                float p2 = __expf(s[j][nq][2] - mnew);
                float p3 = __expf(s[j][nq][3] - mnew);
                ls += (p0 + p1) + (p2 + p3);
                int c0 = (j * 2 + (lg >> 1)) ^ lm7;
                uint2 wv;
                wv.x = pk2(p0, p1);
                wv.y = pk2(p2, p3);
                *(uint2*)&PsW[(nq * 16 + lm) * 128 + c0 * 8 + (lg & 1) * 4] = wv;
            }
            ls += __shfl_xor(ls, 16);
            ls += __shfl_xor(ls, 32);
            lrow[nq] = lrow[nq] * alpha[nq] + ls;
        }
        // rescale O (alpha: softmax layout -> O C-layout via shfl)
#pragma unroll
        for (int mq = 0; mq < 2; ++mq)
#pragma unroll
            for (int r = 0; r < 4; ++r) {
                float al = __shfl(alpha[mq], lg * 4 + r);
#pragma unroll
                for (int n = 0; n < 8; ++n) o[mq][n][r] *= al;
            }
        // O += P V : A = P (wave-private LDS), B = V^T fragments straight from global (L2)
#pragma unroll
        for (int k2 = 0; k2 < 4; ++k2) {
            int cc = (k2 * 4 + lg) ^ lm7;
            bfv8 pa0 = *(const bfv8*)&PsW[lm * 128 + cc * 8];
            bfv8 pa1 = *(const bfv8*)&PsW[(16 + lm) * 128 + cc * 8];
            bfv8 vf[8];
#pragma unroll
            for (int n = 0; n < 8; ++n)
                vf[n] = *(const bfv8*)(vbase + (size_t)(n * 16 + lm) * SEQ + kt + (k2 * 4 + lg) * 8);
#pragma unroll
            for (int n = 0; n < 8; ++n) {
                o[0][n] = __builtin_amdgcn_mfma_f32_16x16x32_bf16(pa0, vf[n], o[0][n], 0, 0, 0);
                o[1][n] = __builtin_amdgcn_mfma_f32_16x16x32_bf16(pa1, vf[n], o[1][n], 0, 0, 0);
            }
        }
    }
    // epilogue: rows q0 + wq*32 + mq*16 + lg*4 + r, cols h*128 + n*16 + lm
#pragma unroll
    for (int mq = 0; mq < 2; ++mq) {
        float linv[4];
#pragma unroll
        for (int r = 0; r < 4; ++r) linv[r] = 1.0f / __shfl(lrow[mq], lg * 4 + r);
        int qrow = q0 + wq * 32 + mq * 16 + lg * 4;
        unsigned short* op = ob + (size_t)(b * SEQ + qrow) * DMODEL + h * HEADD + lm;
#pragma unroll
        for (int n = 0; n < 8; ++n)
#pragma unroll
            for (int r = 0; r < 4; ++r)
                op[(size_t)r * DMODEL + n * 16] = f2bf(o[mq][n][r] * linv[r]);
    }
}

// ---------- launch ----------
extern "C" void kernel_launch(void* const* d_in, const int* in_sizes, int n_in,
                              void* d_out, int out_size, void* d_ws, size_t ws_size,
                              hipStream_t stream) {
    const float* x   = (const float*)d_in[0];
    const float* wq  = (const float*)d_in[1];
    const float* wk  = (const float*)d_in[2];
    const float* wv  = (const float*)d_in[3];
    const float* wo  = (const float*)d_in[4];
    const float* qnw = (const float*)d_in[5];
    const float* knw = (const float*)d_in[6];
    const int*   wsz = (const int*)d_in[7];
    float* out = (float*)d_out;

    // workspace layout (~101 MB); cvt_all dst = [xb | w1 | w2 | w3 | w4] contiguous
    char* ws = (char*)d_ws;
    unsigned short* xb  = (unsigned short*)(ws);                 // 16.78 MB (x bf16; reused for attn out)
    unsigned short* w1  = (unsigned short*)(ws + 16777216);      // wq \  contiguous ->
    unsigned short* w4  = (unsigned short*)(ws + 41943040);      // wo
    unsigned short* qbf = (unsigned short*)(ws + 50331648);      // 16.78 MB bf16 Q (rope+LN+scale)
    unsigned short* kbf = (unsigned short*)(ws + 67108864);      // 16.78 MB bf16 K (rope+LN)
    unsigned short* vtb = (unsigned short*)(ws + 83886080);      // 16.78 MB bf16 V^T

    cvt_all<<<24576, 256, 0, stream>>>(x, wq, wk, wv, wo, xb);

    gemm_qkv<<<dim3(3 * DMODEL / 128, MROWS / 128), 256, 0, stream>>>(xb, w1, qbf, kbf, vtb, qnw, knw);

    attn_mfma<<<(SEQ / AQT) * NHEADS * BATCH, 256, 0, stream>>>(qbf, kbf, vtb, xb, wsz);

    gemm_bt<<<dim3(DMODEL / 128, MROWS / 128), 256, 0, stream>>>(xb, w4, out, MROWS, DMODEL, DMODEL);
}